// Round 8
// baseline (382.312 us; speedup 1.0000x reference)
//
#include <hip/hip_runtime.h>
#include <math.h>

namespace {

constexpr int B = 16, H = 512, W = 512;
constexpr int HWc = H * W;                 // 262144
constexpr size_t Nc = (size_t)B * HWc;     // 4194304

// Strip geometry: 64-lane wave holds cols [strip*42-11, strip*42+52].
// Boundary stencil (3x3) corrupts lanes 0,63; each of the 10 dilation steps
// corrupts one more lane per side -> valid central lanes 11..52 = 42 cols.
// 13 strips x 42 = 546 >= 512 (mask col < 512). Exact tiling, no overlap.
constexpr int NSTRIP = 13;
constexpr int CENT = 42;
constexpr int NBAND = 16;  // 512 / 32 rows
constexpr int NWORK = NSTRIP * NBAND * B * 2;  // 6656 wave work items
constexpr int NSB_HALF = NWORK / 2 / 4;        // 832 blocks per stencil half
constexpr int NBCE = B * 64;                   // 1024 bce partial blocks

// ---------------- DPP lane shifts ----------------
// wave_shr:1 (0x138): lane i <- lane i-1 (lane 0 keeps own -> replicate edge)
// wave_shl:1 (0x130): lane i <- lane i+1 (lane 63 keeps own)
template <int CTRL>
__device__ __forceinline__ float dpp_shift1(float v) {
  int i = __float_as_int(v);
  int r = __builtin_amdgcn_update_dpp(i, i, CTRL, 0xF, 0xF, false);
  return __int_as_float(r);
}

// R5 post-mortem: NO inline-asm max3 -- asm "v" constraints pin the live set
// to the VGPR half of the unified file and a[52]+o[32] spill (539 MB scratch,
// 411 us). Plain fmaxf/fminf trees: clang fuses to v_max3/v_min3 itself.
__device__ __forceinline__ float hmax3(float v) {
  return fmaxf(fmaxf(dpp_shift1<0x138>(v), v), dpp_shift1<0x130>(v));
}
// Boundary builds need max AND min of the same 3 lanes: share the two DPP
// shifts explicitly.
__device__ __forceinline__ void hminmax3(float v, float& mx, float& mn) {
  float s1 = dpp_shift1<0x138>(v);
  float s2 = dpp_shift1<0x130>(v);
  mx = fmaxf(fmaxf(s1, v), s2);
  mn = fminf(fminf(s1, v), s2);
}

__device__ __forceinline__ float wave_sum(float v) {
#pragma unroll
  for (int off = 32; off > 0; off >>= 1) v += __shfl_down(v, off);
  return v;
}

// --- block-wide sum over 256 threads (4 waves of 64). Valid on tid==0 only.
__device__ __forceinline__ float block_reduce_256(float v, float* sm, int tid) {
#pragma unroll
  for (int off = 32; off > 0; off >>= 1) v += __shfl_down(v, off);
  int lane = tid & 63, wid = tid >> 6;
  if (lane == 0) sm[wid] = v;
  __syncthreads();
  float r = 0.f;
  if (tid == 0) r = sm[0] + sm[1] + sm[2] + sm[3];
  __syncthreads();
  return r;
}

// CH==0: src map = sigmoid(logits), oth map = target.
// CH==1: src map = target,          oth map = sigmoid(logits).
template <int CH>
__device__ __forceinline__ float load_src(const float* __restrict__ Lg,
                                          const int* __restrict__ Tg, int gy,
                                          int colc) {
  gy = min(max(gy, 0), H - 1);  // scalar clamp (gy wave-uniform)
  if constexpr (CH == 0) {
    float x = Lg[gy * W + colc];
    float e = __expf(-x);
    return __builtin_amdgcn_rcpf(1.f + e);
  } else {
    return (float)Tg[gy * W + colc];
  }
}

// ---- dilation steps via template recursion (R2: compile-time D keeps all
// indices constant -> arrays stay register-resident).
// R4: accv[4] -- single acc was a 320-deep dependent FMA chain.
template <int D>
__device__ __forceinline__ void dilate_steps(float (&a)[52],
                                             const float (&o)[32],
                                             float (&accv)[4]) {
  if constexpr (D <= 10) {
    float hp = hmax3(a[D - 1]);
    float hc = hmax3(a[D]);
#pragma unroll
    for (int r = D; r <= 51 - D; ++r) {  // trip count 52-2D: compile-time
      float hn = hmax3(a[r + 1]);
      float nv = fmaxf(fmaxf(hp, hc), hn);
      hp = hc;
      hc = hn;
      a[r] = nv;
    }
    constexpr float wd = 0.1f * (float)D;
#pragma unroll
    for (int k = 0; k < 32; ++k) accv[k & 3] += wd * fabsf(a[10 + k] - o[k]);
    dilate_steps<D + 1>(a, o, accv);
  }
}

// ---------------- stencil wave body -----------------------------------------
template <int CH>
__device__ __forceinline__ void fused_body(const float* __restrict__ Lg,
                                           const int* __restrict__ Tg,
                                           int lane, int strip, int band,
                                           int bz,
                                           float* __restrict__ chain_p) {
  int col = strip * CENT - 11 + lane;
  int colc = min(max(col, 0), W - 1);
  int y0 = band * 32;

  // ---- other-map boundary, central rows y0..y0+31 (rolling 3-row stencil)
  float o[32];
  {
    float v0 = load_src<1 - CH>(Lg, Tg, y0 - 1, colc);
    float v1 = load_src<1 - CH>(Lg, Tg, y0, colc);
    float hx0, hn0, hx1, hn1;
    hminmax3(v0, hx0, hn0);
    hminmax3(v1, hx1, hn1);
#pragma unroll
    for (int k = 0; k < 32; ++k) {
      float v2 = load_src<1 - CH>(Lg, Tg, y0 + 1 + k, colc);
      float hx2, hn2;
      hminmax3(v2, hx2, hn2);
      o[k] = fmaxf(fmaxf(hx0, hx1), hx2) - fminf(fminf(hn0, hn1), hn2);
      hx0 = hx1;
      hx1 = hx2;
      hn0 = hn1;
      hn1 = hn2;
    }
  }

  // ---- src-map boundary incl. vertical halo: rows y0-10 .. y0+41
  float a[52];
  {
    float v0 = load_src<CH>(Lg, Tg, y0 - 11, colc);
    float v1 = load_src<CH>(Lg, Tg, y0 - 10, colc);
    float hx0, hn0, hx1, hn1;
    hminmax3(v0, hx0, hn0);
    hminmax3(v1, hx1, hn1);
#pragma unroll
    for (int r = 0; r < 52; ++r) {
      float v2 = load_src<CH>(Lg, Tg, y0 - 9 + r, colc);
      float hx2, hn2;
      hminmax3(v2, hx2, hn2);
      a[r] = fmaxf(fmaxf(hx0, hx1), hx2) - fminf(fminf(hn0, hn1), hn2);
      hx0 = hx1;
      hx1 = hx2;
      hn0 = hn1;
      hn1 = hn2;
    }
  }

  // ---- 10-step register-resident dilation + weighted L1 accumulation
  float accv[4] = {0.f, 0.f, 0.f, 0.f};
  dilate_steps<1>(a, o, accv);
  float acc = (accv[0] + accv[1]) + (accv[2] + accv[3]);

  bool valid = (lane >= 11 && lane <= 52 && col < W);
  acc = valid ? acc : 0.f;
  acc = wave_sum(acc);
  if (lane == 0) chain_p[(bz * NBAND + band) * NSTRIP + strip] = acc;
}

// Common dispatch for a half-batch of images (img_base .. img_base+7).
// widx in [0, 3328): strip 13 x band 16 x z 16 where z = chain*8 + (img-base).
__device__ __forceinline__ void stencil_dispatch(
    const float* __restrict__ logits, const int* __restrict__ target,
    float* __restrict__ chain_p, int img_base, int blk) {
  int tid = threadIdx.x;
  int lane = tid & 63;
  int wv = __builtin_amdgcn_readfirstlane(tid >> 6);
  int widx = blk * 4 + wv;  // 0..3327
  int strip = widx % NSTRIP;
  int rest = widx / NSTRIP;   // 0..255
  int band = rest & 15;
  int z = rest >> 4;          // 0..15
  int img = (z & 7) + img_base;
  int chain = z >> 3;
  int bz = chain * 16 + img;  // global chain-image index, 0..31
  const float* Lg = logits + (size_t)img * HWc;
  const int* Tg = target + (size_t)img * HWc;
  if (chain == 0)
    fused_body<0>(Lg, Tg, lane, strip, band, bz, chain_p);
  else
    fused_body<1>(Lg, Tg, lane, strip, band, bz, chain_p);
}

// ---------------- A/B pair: identical work, different register budgets ------
// R7 post-mortem: VGPR_Count=60 with ~95 live values and zero scratch means
// a[]/o[] live in the AGPR half of the unified file; if VOP3 (v_max3) can't
// take AGPR operands directly, every array access in the dilation pays a
// v_accvgpr_read/write mov (~+2k instr/wave -- exactly the unexplained 2x
// between hand-counted ~4.2k and measured ~8.4k instr/wave).
// A: (256,4) = proven shape, ~128-reg budget, compiler splits VGPR+AGPR.
// B: (256,3) = ~170-reg budget: live set fits in arch VGPRs, no cross-file
//    movs. Effective occupancy measured at 2.5-3 waves/SIMD anyway.
// Counters disambiguate: VGPR_Count_B >> 60 proves allocation obeyed;
// dur_B vs dur_A proves/refutes the mov cost.
__global__ void __launch_bounds__(256, 4) sten_a(
    const float* __restrict__ logits, const int* __restrict__ target,
    float* __restrict__ chain_p) {
  stencil_dispatch(logits, target, chain_p, 0, blockIdx.x);
}
__global__ void __launch_bounds__(256, 3) sten_b(
    const float* __restrict__ logits, const int* __restrict__ target,
    float* __restrict__ chain_p) {
  stencil_dispatch(logits, target, chain_p, 8, blockIdx.x);
}

// ---------------- BCE kernel (standalone again, pure A/B halves above) ------
// Identity: max(x,0) - x*t + log1p(exp(-|x|)) == x*(1-t) + log(1+e^-x).
__global__ void __launch_bounds__(256) bce_kernel(
    const float* __restrict__ logits, const int* __restrict__ target,
    float* __restrict__ bceA, float* __restrict__ spA,
    float* __restrict__ stA, float* __restrict__ sptA) {
  __shared__ float smr[4];
  int blk = blockIdx.x;
  int img = blk >> 6, seg = blk & 63;  // 64 blocks/image
  const float4* L4 =
      (const float4*)(logits + (size_t)img * HWc + (size_t)seg * 4096);
  const int4* T4 =
      (const int4*)(target + (size_t)img * HWc + (size_t)seg * 4096);
  int tid = threadIdx.x;
  float s_bce = 0.f, s_p = 0.f, s_t = 0.f, s_pt = 0.f;
#pragma unroll
  for (int it = 0; it < 4; ++it) {
    float4 x4 = L4[it * 256 + tid];
    int4 t4 = T4[it * 256 + tid];
    float xs[4] = {x4.x, x4.y, x4.z, x4.w};
    int ts[4] = {t4.x, t4.y, t4.z, t4.w};
#pragma unroll
    for (int j = 0; j < 4; ++j) {
      float x = xs[j];
      float tf = (float)ts[j];
      float e = __expf(-x);
      float p = __builtin_amdgcn_rcpf(1.f + e);
      s_p += p;
      s_t += tf;
      s_pt += p * tf;
      s_bce += x * (1.f - tf) + __logf(1.f + e);
    }
  }
  float r;
  r = block_reduce_256(s_bce, smr, tid);
  if (tid == 0) bceA[blk] = r;
  r = block_reduce_256(s_p, smr, tid);
  if (tid == 0) spA[blk] = r;
  r = block_reduce_256(s_t, smr, tid);
  if (tid == 0) stA[blk] = r;
  r = block_reduce_256(s_pt, smr, tid);
  if (tid == 0) sptA[blk] = r;
}

// ---------------- finalize ----------------
__global__ void finalize_kernel(const float* __restrict__ bceA,
                                const float* __restrict__ spA,
                                const float* __restrict__ stA,
                                const float* __restrict__ sptA,
                                const float* __restrict__ chain_p,
                                float* __restrict__ out) {
  __shared__ float smr[4];
  __shared__ float smImg[16][3];
  __shared__ double smd[16][2];
  int tid = threadIdx.x;

  float s = 0.f;
  for (int i = tid; i < NBCE; i += 256) s += bceA[i];  // 1024
  float bce_sum = block_reduce_256(s, smr, tid);

  s = 0.f;
  for (int i = tid; i < NWORK; i += 256) s += chain_p[i];  // 6656
  float hd_sum = block_reduce_256(s, smr, tid);

  {
    int img = tid >> 4, part = tid & 15;  // 16 threads per image
    float sp = 0.f, st = 0.f, spt = 0.f;
    for (int j = part; j < 64; j += 16) {  // 64 partials/image, 4 iters
      int idx = img * 64 + j;
      sp += spA[idx];
      st += stA[idx];
      spt += sptA[idx];
    }
#pragma unroll
    for (int off = 8; off > 0; off >>= 1) {
      sp += __shfl_down(sp, off, 16);
      st += __shfl_down(st, off, 16);
      spt += __shfl_down(spt, off, 16);
    }
    if (part == 0) {
      smImg[img][0] = sp;
      smImg[img][1] = st;
      smImg[img][2] = spt;
    }
  }
  __syncthreads();
  if (tid < 16) {
    double sp = smImg[tid][0], st = smImg[tid][1], spt = smImg[tid][2];
    double dice = (2.0 * spt + 1e-6) / (sp + st + 1e-6 + 1e-7);
    double tv = (spt + 1e-6) /
                (spt + 0.7 * (sp - spt) + 0.3 * (st - spt) + 1e-6 + 1e-7);
    smd[tid][0] = 1.0 - dice;
    smd[tid][1] = pow(1.0 - tv, 0.75);
  }
  __syncthreads();
  if (tid == 0) {
    double dice_l = 0.0, ft_l = 0.0;
    for (int i = 0; i < 16; ++i) {
      dice_l += smd[i][0];
      ft_l += smd[i][1];
    }
    dice_l /= 16.0;
    ft_l /= 16.0;
    const double Nd = (double)Nc;
    double bce = (double)bce_sum / Nd;
    double hd = ((double)hd_sum / Nd) / (5.5 + 1e-8);
    out[0] = (float)(bce + dice_l + ft_l + 0.1 * hd);
  }
}

}  // namespace

extern "C" void kernel_launch(void* const* d_in, const int* in_sizes, int n_in,
                              void* d_out, int out_size, void* d_ws,
                              size_t ws_size, hipStream_t stream) {
  const float* logits = (const float*)d_in[0];
  const int* target = (const int*)d_in[1];
  float* out = (float*)d_out;

  // Workspace: only small partial arrays. All fully written each launch.
  float* part = (float*)d_ws;
  float* bceA = part;                  // 1024
  float* spA = part + NBCE;            // 1024
  float* stA = part + 2 * NBCE;        // 1024
  float* sptA = part + 3 * NBCE;       // 1024
  float* chain_p = part + 4 * NBCE;    // 6656 = 32*16*13

  bce_kernel<<<dim3(NBCE), dim3(256), 0, stream>>>(logits, target, bceA, spA,
                                                   stA, sptA);
  sten_a<<<dim3(NSB_HALF), dim3(256), 0, stream>>>(logits, target, chain_p);
  sten_b<<<dim3(NSB_HALF), dim3(256), 0, stream>>>(logits, target, chain_p);
  finalize_kernel<<<1, 256, 0, stream>>>(bceA, spA, stA, sptA, chain_p, out);
}

// Round 9
// 180.438 us; speedup vs baseline: 2.1188x; 2.1188x over previous
//
#include <hip/hip_runtime.h>
#include <math.h>

namespace {

constexpr int B = 16, H = 512, W = 512;
constexpr int HWc = H * W;                 // 262144
constexpr size_t Nc = (size_t)B * HWc;     // 4194304

// Strip geometry: 64-lane wave holds cols [strip*42-11, strip*42+52].
// Boundary stencil (3x3) corrupts lanes 0,63; each of the 10 dilation steps
// corrupts one more lane per side -> valid central lanes 11..52 = 42 cols.
// 13 strips x 42 = 546 >= 512 (mask col < 512). Exact tiling, no overlap.
constexpr int NSTRIP = 13;
constexpr int CENT = 42;
constexpr int NBAND = 16;  // 512 / 32 rows
constexpr int NWORK = NSTRIP * NBAND * B * 2;  // 6656 wave work items
constexpr int NSB = NWORK / 4;                 // 1664 stencil blocks
constexpr int NBCE = B * 64;                   // 1024 bce blocks
constexpr int NBLOCKS = NSB + NBCE;            // 2688

// Accumulator layout in workspace (floats), zeroed by hipMemsetAsync:
//  A[0..63]    hd slots        (stencil waves, slot = widx & 63)
//  A[64..79]   bce slots       (bce blocks, slot = blk & 15)
//  A[80..95]   sp per image
//  A[96..111]  st per image
//  A[112..127] spt per image
//  ((unsigned*)A)[128] = done-counter
// R8 post-mortem: partials->finalize_kernel cost ~10us of launch gap +
// 1-block latency; folded into the fused kernel via last-block-done.

// ---------------- DPP lane shifts ----------------
// wave_shr:1 (0x138): lane i <- lane i-1 (lane 0 keeps own -> replicate edge)
// wave_shl:1 (0x130): lane i <- lane i+1 (lane 63 keeps own)
template <int CTRL>
__device__ __forceinline__ float dpp_shift1(float v) {
  int i = __float_as_int(v);
  int r = __builtin_amdgcn_update_dpp(i, i, CTRL, 0xF, 0xF, false);
  return __int_as_float(r);
}

// R5 post-mortem: NO inline-asm max3 -- asm "v" constraints pin the live set
// to the VGPR half of the unified file and a[52]+o[32] spill (539 MB scratch,
// 411 us). Plain fmaxf/fminf trees: clang fuses to v_max3/v_min3 itself.
// R8 post-mortem: and NO __launch_bounds__ loosening -- (256,3) made the
// compiler choose memory spill (221 MB) over the AGPR split. (256,4) only.
__device__ __forceinline__ float hmax3(float v) {
  return fmaxf(fmaxf(dpp_shift1<0x138>(v), v), dpp_shift1<0x130>(v));
}
__device__ __forceinline__ void hminmax3(float v, float& mx, float& mn) {
  float s1 = dpp_shift1<0x138>(v);
  float s2 = dpp_shift1<0x130>(v);
  mx = fmaxf(fmaxf(s1, v), s2);
  mn = fminf(fminf(s1, v), s2);
}

__device__ __forceinline__ float wave_sum(float v) {
#pragma unroll
  for (int off = 32; off > 0; off >>= 1) v += __shfl_down(v, off);
  return v;
}

__device__ __forceinline__ double wave_sum_d(double v) {
#pragma unroll
  for (int off = 32; off > 0; off >>= 1) v += __shfl_down(v, off);
  return v;
}

// --- block-wide sum over 256 threads (4 waves of 64). Valid on tid==0 only.
__device__ __forceinline__ float block_reduce_256(float v, float* sm, int tid) {
#pragma unroll
  for (int off = 32; off > 0; off >>= 1) v += __shfl_down(v, off);
  int lane = tid & 63, wid = tid >> 6;
  if (lane == 0) sm[wid] = v;
  __syncthreads();
  float r = 0.f;
  if (tid == 0) r = sm[0] + sm[1] + sm[2] + sm[3];
  __syncthreads();
  return r;
}

// CH==0: src map = sigmoid(logits), oth map = target.
// CH==1: src map = target,          oth map = sigmoid(logits).
template <int CH>
__device__ __forceinline__ float load_src(const float* __restrict__ Lg,
                                          const int* __restrict__ Tg, int gy,
                                          int colc) {
  gy = min(max(gy, 0), H - 1);  // wave-uniform clamp
  if constexpr (CH == 0) {
    float x = Lg[gy * W + colc];
    float e = __expf(-x);
    return __builtin_amdgcn_rcpf(1.f + e);
  } else {
    return (float)Tg[gy * W + colc];
  }
}

// ---- dilation steps via template recursion (R2: compile-time D keeps all
// indices constant -> arrays stay register-resident).
// R4: accv[4] -- single acc was a 320-deep dependent FMA chain.
template <int D>
__device__ __forceinline__ void dilate_steps(float (&a)[52],
                                             const float (&o)[32],
                                             float (&accv)[4]) {
  if constexpr (D <= 10) {
    float hp = hmax3(a[D - 1]);
    float hc = hmax3(a[D]);
#pragma unroll
    for (int r = D; r <= 51 - D; ++r) {  // trip count 52-2D: compile-time
      float hn = hmax3(a[r + 1]);
      float nv = fmaxf(fmaxf(hp, hc), hn);
      hp = hc;
      hc = hn;
      a[r] = nv;
    }
    constexpr float wd = 0.1f * (float)D;
#pragma unroll
    for (int k = 0; k < 32; ++k) accv[k & 3] += wd * fabsf(a[10 + k] - o[k]);
    dilate_steps<D + 1>(a, o, accv);
  }
}

// ---------------- stencil wave body -----------------------------------------
template <int CH>
__device__ __forceinline__ void fused_body(const float* __restrict__ Lg,
                                           const int* __restrict__ Tg,
                                           int lane, int strip, int band,
                                           int slot, float* __restrict__ A) {
  int col = strip * CENT - 11 + lane;
  int colc = min(max(col, 0), W - 1);
  int y0 = band * 32;

  // ---- other-map boundary, central rows y0..y0+31 (rolling 3-row stencil)
  float o[32];
  {
    float v0 = load_src<1 - CH>(Lg, Tg, y0 - 1, colc);
    float v1 = load_src<1 - CH>(Lg, Tg, y0, colc);
    float hx0, hn0, hx1, hn1;
    hminmax3(v0, hx0, hn0);
    hminmax3(v1, hx1, hn1);
#pragma unroll
    for (int k = 0; k < 32; ++k) {
      float v2 = load_src<1 - CH>(Lg, Tg, y0 + 1 + k, colc);
      float hx2, hn2;
      hminmax3(v2, hx2, hn2);
      o[k] = fmaxf(fmaxf(hx0, hx1), hx2) - fminf(fminf(hn0, hn1), hn2);
      hx0 = hx1;
      hx1 = hx2;
      hn0 = hn1;
      hn1 = hn2;
    }
  }

  // ---- src-map boundary incl. vertical halo: rows y0-10 .. y0+41
  float a[52];
  {
    float v0 = load_src<CH>(Lg, Tg, y0 - 11, colc);
    float v1 = load_src<CH>(Lg, Tg, y0 - 10, colc);
    float hx0, hn0, hx1, hn1;
    hminmax3(v0, hx0, hn0);
    hminmax3(v1, hx1, hn1);
#pragma unroll
    for (int r = 0; r < 52; ++r) {
      float v2 = load_src<CH>(Lg, Tg, y0 - 9 + r, colc);
      float hx2, hn2;
      hminmax3(v2, hx2, hn2);
      a[r] = fmaxf(fmaxf(hx0, hx1), hx2) - fminf(fminf(hn0, hn1), hn2);
      hx0 = hx1;
      hx1 = hx2;
      hn0 = hn1;
      hn1 = hn2;
    }
  }

  // ---- 10-step register-resident dilation + weighted L1 accumulation
  float accv[4] = {0.f, 0.f, 0.f, 0.f};
  dilate_steps<1>(a, o, accv);
  float acc = (accv[0] + accv[1]) + (accv[2] + accv[3]);

  bool valid = (lane >= 11 && lane <= 52 && col < W);
  acc = valid ? acc : 0.f;
  acc = wave_sum(acc);
  if (lane == 0) atomicAdd(&A[slot], acc);  // 64 slots: no contention
}

// ---------------- BCE block body --------------------------------------------
// Identity: max(x,0) - x*t + log1p(exp(-|x|)) == x*(1-t) + log(1+e^-x).
__device__ __forceinline__ void bce_body(const float* __restrict__ logits,
                                         const int* __restrict__ target,
                                         int blk, float* __restrict__ A,
                                         float* sm) {
  int img = blk >> 6, seg = blk & 63;  // 64 blocks/image
  const float4* L4 =
      (const float4*)(logits + (size_t)img * HWc + (size_t)seg * 4096);
  const int4* T4 =
      (const int4*)(target + (size_t)img * HWc + (size_t)seg * 4096);
  int tid = threadIdx.x;
  float s_bce = 0.f, s_p = 0.f, s_t = 0.f, s_pt = 0.f;
#pragma unroll
  for (int it = 0; it < 4; ++it) {
    float4 x4 = L4[it * 256 + tid];
    int4 t4 = T4[it * 256 + tid];
    float xs[4] = {x4.x, x4.y, x4.z, x4.w};
    int ts[4] = {t4.x, t4.y, t4.z, t4.w};
#pragma unroll
    for (int j = 0; j < 4; ++j) {
      float x = xs[j];
      float tf = (float)ts[j];
      float e = __expf(-x);
      float p = __builtin_amdgcn_rcpf(1.f + e);
      s_p += p;
      s_t += tf;
      s_pt += p * tf;
      s_bce += x * (1.f - tf) + __logf(1.f + e);
    }
  }
  float r;
  r = block_reduce_256(s_bce, sm, tid);
  if (tid == 0) atomicAdd(&A[64 + (blk & 15)], r);
  r = block_reduce_256(s_p, sm, tid);
  if (tid == 0) atomicAdd(&A[80 + img], r);
  r = block_reduce_256(s_t, sm, tid);
  if (tid == 0) atomicAdd(&A[96 + img], r);
  r = block_reduce_256(s_pt, sm, tid);
  if (tid == 0) atomicAdd(&A[112 + img], r);
}

// Coherent read of an atomically-accumulated slot (cross-XCD safe: RMW goes
// to the device coherence point; a plain load could hit a stale local L2).
__device__ __forceinline__ float coherent_read(float* p) {
  return atomicAdd(p, 0.f);
}

// ---------------- last-block combine (wave 0 only) --------------------------
__device__ __forceinline__ void combine(float* __restrict__ A,
                                        float* __restrict__ out, int tid) {
  if (tid >= 64) return;
  // hd: 64 slots, one per lane.
  double v_hd = (double)coherent_read(&A[tid]);
  v_hd = wave_sum_d(v_hd);
  // bce: 16 slots on lanes 0..15, zeros elsewhere.
  double v_bce = (tid < 16) ? (double)coherent_read(&A[64 + tid]) : 0.0;
  v_bce = wave_sum_d(v_bce);
  // per-image dice / focal-tversky terms on lanes 0..15.
  double t_dice = 0.0, t_ft = 0.0;
  if (tid < 16) {
    double sp = (double)coherent_read(&A[80 + tid]);
    double st = (double)coherent_read(&A[96 + tid]);
    double spt = (double)coherent_read(&A[112 + tid]);
    double dice = (2.0 * spt + 1e-6) / (sp + st + 1e-6 + 1e-7);
    double tv = (spt + 1e-6) /
                (spt + 0.7 * (sp - spt) + 0.3 * (st - spt) + 1e-6 + 1e-7);
    t_dice = 1.0 - dice;
    // x^0.75 = sqrt(x)*sqrt(sqrt(x)) -- avoids inlining libm pow into this
    // kernel (register-pressure hazard for the stencil path). ~2-3 ulp f32.
    float xs = (float)(1.0 - tv);
    t_ft = (double)(sqrtf(xs) * sqrtf(sqrtf(xs)));
  }
  t_dice = wave_sum_d(t_dice);
  t_ft = wave_sum_d(t_ft);
  if (tid == 0) {
    const double Nd = (double)Nc;
    double bce = v_bce / Nd;
    double hd = (v_hd / Nd) / (5.5 + 1e-8);
    out[0] = (float)(bce + t_dice / 16.0 + t_ft / 16.0 + 0.1 * hd);
  }
}

// ---------------- merged kernel ---------------------------------------------
// Stencil blocks FIRST (long poles start earliest; memory-bound BCE blocks
// backfill the drain). Tail: device-scope done-counter; last block to finish
// runs the combine inline -- removes the finalize launch + gap.
// __launch_bounds__(256, 4): the ONLY proven shape (R5/R8: anything else
// triggers scratch spill).
__global__ void __launch_bounds__(256, 4) fused_kernel(
    const float* __restrict__ logits, const int* __restrict__ target,
    float* __restrict__ A, unsigned* __restrict__ counter,
    float* __restrict__ out) {
  __shared__ float sm[4];
  __shared__ unsigned s_old;
  int tid = threadIdx.x;

  if (blockIdx.x < NSB) {
    int lane = tid & 63;
    int wv = __builtin_amdgcn_readfirstlane(tid >> 6);
    int widx = blockIdx.x * 4 + wv;  // 0..6655, exact
    int strip = widx % NSTRIP;
    int rest = widx / NSTRIP;
    int band = rest & 15;
    int bz = rest >> 4;  // 0..31
    int img = bz & 15, chain = bz >> 4;
    const float* Lg = logits + (size_t)img * HWc;
    const int* Tg = target + (size_t)img * HWc;
    int slot = widx & 63;
    if (chain == 0)
      fused_body<0>(Lg, Tg, lane, strip, band, slot, A);
    else
      fused_body<1>(Lg, Tg, lane, strip, band, slot, A);
  } else {
    bce_body(logits, target, blockIdx.x - NSB, A, sm);
  }

  // ---- done-counting tail. __syncthreads drains every wave's atomics
  // (vmcnt(0) before s_barrier); __threadfence orders tid0's own ops.
  __syncthreads();
  if (tid == 0) {
    __threadfence();
    s_old = atomicAdd(counter, 1u);
  }
  __syncthreads();
  if (s_old == (unsigned)(NBLOCKS - 1)) combine(A, out, tid);
}

}  // namespace

extern "C" void kernel_launch(void* const* d_in, const int* in_sizes, int n_in,
                              void* d_out, int out_size, void* d_ws,
                              size_t ws_size, hipStream_t stream) {
  const float* logits = (const float*)d_in[0];
  const int* target = (const int*)d_in[1];
  float* out = (float*)d_out;

  float* A = (float*)d_ws;                     // 128 accum slots
  unsigned* counter = (unsigned*)(A + 128);    // done counter

  // Zero accumulators + counter (workspace is re-poisoned between runs).
  hipMemsetAsync(d_ws, 0, 1024, stream);

  fused_kernel<<<dim3(NBLOCKS), dim3(256), 0, stream>>>(logits, target, A,
                                                        counter, out);
}

// Round 10
// 179.950 us; speedup vs baseline: 2.1246x; 1.0027x over previous
//
#include <hip/hip_runtime.h>
#include <math.h>

namespace {

constexpr int B = 16, H = 512, W = 512;
constexpr int HWc = H * W;                 // 262144
constexpr size_t Nc = (size_t)B * HWc;     // 4194304

// Strip geometry: 64-lane wave holds cols [strip*42-11, strip*42+52].
// Boundary stencil (3x3) corrupts lanes 0,63; each of the 10 dilation steps
// corrupts one more lane per side -> valid central lanes 11..52 = 42 cols.
// 13 strips x 42 = 546 >= 512 (mask col < 512). Exact tiling, no overlap.
constexpr int NSTRIP = 13;
constexpr int CENT = 42;
constexpr int NBAND = 16;  // 512 / 32 rows
constexpr int NWORK = NSTRIP * NBAND * B * 2;  // 6656 wave work items
constexpr int NSB = NWORK / 4;                 // 1664 stencil blocks
constexpr int NBCE = B * 64;                   // 1024 bce blocks
constexpr int NBLOCKS = NSB + NBCE;            // 2688

// R9 post-mortem: ~10.7k fp atomicAdd RMWs into 4-8 cache lines serialized at
// the coherence point and every block WAITED on its RMW at the tail barrier
// -> +55us stall (VALUBusy 75->42%). Transport fixed: contention-free
// DISTINCT-address cache-bypassing stores (no RMW); only the done-counter
// remains an RMW (1 integer per block).
__device__ __forceinline__ void astore(float* p, float v) {
  __hip_atomic_store(p, v, __ATOMIC_RELAXED, __HIP_MEMORY_SCOPE_AGENT);
}
__device__ __forceinline__ float aload(const float* p) {
  return __hip_atomic_load(p, __ATOMIC_RELAXED, __HIP_MEMORY_SCOPE_AGENT);
}

// ---------------- DPP lane shifts ----------------
// wave_shr:1 (0x138): lane i <- lane i-1 (lane 0 keeps own -> replicate edge)
// wave_shl:1 (0x130): lane i <- lane i+1 (lane 63 keeps own)
template <int CTRL>
__device__ __forceinline__ float dpp_shift1(float v) {
  int i = __float_as_int(v);
  int r = __builtin_amdgcn_update_dpp(i, i, CTRL, 0xF, 0xF, false);
  return __int_as_float(r);
}

// R5: NO inline-asm max3 (pins live set to VGPR half -> spill). R8: NO
// __launch_bounds__ loosening ((256,3) chose spill over AGPR split).
__device__ __forceinline__ float hmax3(float v) {
  return fmaxf(fmaxf(dpp_shift1<0x138>(v), v), dpp_shift1<0x130>(v));
}
__device__ __forceinline__ void hminmax3(float v, float& mx, float& mn) {
  float s1 = dpp_shift1<0x138>(v);
  float s2 = dpp_shift1<0x130>(v);
  mx = fmaxf(fmaxf(s1, v), s2);
  mn = fminf(fminf(s1, v), s2);
}

__device__ __forceinline__ float wave_sum(float v) {
#pragma unroll
  for (int off = 32; off > 0; off >>= 1) v += __shfl_down(v, off);
  return v;
}

// --- block-wide sum over 256 threads (4 waves of 64). Valid on tid==0 only.
__device__ __forceinline__ float block_reduce_256(float v, float* sm, int tid) {
#pragma unroll
  for (int off = 32; off > 0; off >>= 1) v += __shfl_down(v, off);
  int lane = tid & 63, wid = tid >> 6;
  if (lane == 0) sm[wid] = v;
  __syncthreads();
  float r = 0.f;
  if (tid == 0) r = sm[0] + sm[1] + sm[2] + sm[3];
  __syncthreads();
  return r;
}

// CH==0: src map = sigmoid(logits), oth map = target.
// CH==1: src map = target,          oth map = sigmoid(logits).
template <int CH>
__device__ __forceinline__ float load_src(const float* __restrict__ Lg,
                                          const int* __restrict__ Tg, int gy,
                                          int colc) {
  gy = min(max(gy, 0), H - 1);  // wave-uniform clamp
  if constexpr (CH == 0) {
    float x = Lg[gy * W + colc];
    float e = __expf(-x);
    return __builtin_amdgcn_rcpf(1.f + e);
  } else {
    return (float)Tg[gy * W + colc];
  }
}

// ---- dilation steps via template recursion (R2: compile-time D keeps all
// indices constant -> arrays stay register-resident).
// R4: accv[4] -- single acc was a 320-deep dependent FMA chain.
template <int D>
__device__ __forceinline__ void dilate_steps(float (&a)[52],
                                             const float (&o)[32],
                                             float (&accv)[4]) {
  if constexpr (D <= 10) {
    float hp = hmax3(a[D - 1]);
    float hc = hmax3(a[D]);
#pragma unroll
    for (int r = D; r <= 51 - D; ++r) {  // trip count 52-2D: compile-time
      float hn = hmax3(a[r + 1]);
      float nv = fmaxf(fmaxf(hp, hc), hn);
      hp = hc;
      hc = hn;
      a[r] = nv;
    }
    constexpr float wd = 0.1f * (float)D;
#pragma unroll
    for (int k = 0; k < 32; ++k) accv[k & 3] += wd * fabsf(a[10 + k] - o[k]);
    dilate_steps<D + 1>(a, o, accv);
  }
}

// ---------------- stencil wave body (R7-proven) -----------------------------
template <int CH>
__device__ __forceinline__ void fused_body(const float* __restrict__ Lg,
                                           const int* __restrict__ Tg,
                                           int lane, int strip, int band,
                                           int widx,
                                           float* __restrict__ chain_p) {
  int col = strip * CENT - 11 + lane;
  int colc = min(max(col, 0), W - 1);
  int y0 = band * 32;

  // ---- other-map boundary, central rows y0..y0+31 (rolling 3-row stencil)
  float o[32];
  {
    float v0 = load_src<1 - CH>(Lg, Tg, y0 - 1, colc);
    float v1 = load_src<1 - CH>(Lg, Tg, y0, colc);
    float hx0, hn0, hx1, hn1;
    hminmax3(v0, hx0, hn0);
    hminmax3(v1, hx1, hn1);
#pragma unroll
    for (int k = 0; k < 32; ++k) {
      float v2 = load_src<1 - CH>(Lg, Tg, y0 + 1 + k, colc);
      float hx2, hn2;
      hminmax3(v2, hx2, hn2);
      o[k] = fmaxf(fmaxf(hx0, hx1), hx2) - fminf(fminf(hn0, hn1), hn2);
      hx0 = hx1;
      hx1 = hx2;
      hn0 = hn1;
      hn1 = hn2;
    }
  }

  // ---- src-map boundary incl. vertical halo: rows y0-10 .. y0+41
  float a[52];
  {
    float v0 = load_src<CH>(Lg, Tg, y0 - 11, colc);
    float v1 = load_src<CH>(Lg, Tg, y0 - 10, colc);
    float hx0, hn0, hx1, hn1;
    hminmax3(v0, hx0, hn0);
    hminmax3(v1, hx1, hn1);
#pragma unroll
    for (int r = 0; r < 52; ++r) {
      float v2 = load_src<CH>(Lg, Tg, y0 - 9 + r, colc);
      float hx2, hn2;
      hminmax3(v2, hx2, hn2);
      a[r] = fmaxf(fmaxf(hx0, hx1), hx2) - fminf(fminf(hn0, hn1), hn2);
      hx0 = hx1;
      hx1 = hx2;
      hn0 = hn1;
      hn1 = hn2;
    }
  }

  // ---- 10-step register-resident dilation + weighted L1 accumulation
  float accv[4] = {0.f, 0.f, 0.f, 0.f};
  dilate_steps<1>(a, o, accv);
  float acc = (accv[0] + accv[1]) + (accv[2] + accv[3]);

  bool valid = (lane >= 11 && lane <= 52 && col < W);
  acc = valid ? acc : 0.f;
  acc = wave_sum(acc);
  if (lane == 0) astore(&chain_p[widx], acc);  // distinct addr: no contention
}

// ---------------- BCE block body --------------------------------------------
// Identity: max(x,0) - x*t + log1p(exp(-|x|)) == x*(1-t) + log(1+e^-x).
__device__ __forceinline__ void bce_body(const float* __restrict__ logits,
                                         const int* __restrict__ target,
                                         int blk, float* __restrict__ bceA,
                                         float* __restrict__ spA,
                                         float* __restrict__ stA,
                                         float* __restrict__ sptA, float* sm) {
  int img = blk >> 6, seg = blk & 63;  // 64 blocks/image
  const float4* L4 =
      (const float4*)(logits + (size_t)img * HWc + (size_t)seg * 4096);
  const int4* T4 =
      (const int4*)(target + (size_t)img * HWc + (size_t)seg * 4096);
  int tid = threadIdx.x;
  float s_bce = 0.f, s_p = 0.f, s_t = 0.f, s_pt = 0.f;
#pragma unroll
  for (int it = 0; it < 4; ++it) {
    float4 x4 = L4[it * 256 + tid];
    int4 t4 = T4[it * 256 + tid];
    float xs[4] = {x4.x, x4.y, x4.z, x4.w};
    int ts[4] = {t4.x, t4.y, t4.z, t4.w};
#pragma unroll
    for (int j = 0; j < 4; ++j) {
      float x = xs[j];
      float tf = (float)ts[j];
      float e = __expf(-x);
      float p = __builtin_amdgcn_rcpf(1.f + e);
      s_p += p;
      s_t += tf;
      s_pt += p * tf;
      s_bce += x * (1.f - tf) + __logf(1.f + e);
    }
  }
  float r;
  r = block_reduce_256(s_bce, sm, tid);
  if (tid == 0) astore(&bceA[blk], r);
  r = block_reduce_256(s_p, sm, tid);
  if (tid == 0) astore(&spA[blk], r);
  r = block_reduce_256(s_t, sm, tid);
  if (tid == 0) astore(&stA[blk], r);
  r = block_reduce_256(s_pt, sm, tid);
  if (tid == 0) astore(&sptA[blk], r);
}

// ---------------- last-block combine (all 256 threads; R7 finalize logic) ---
__device__ __forceinline__ void combine(
    const float* __restrict__ bceA, const float* __restrict__ spA,
    const float* __restrict__ stA, const float* __restrict__ sptA,
    const float* __restrict__ chain_p, float* __restrict__ out, float* smr,
    float (*smImg)[3], double (*smd)[2], int tid) {
  float s = 0.f;
  for (int i = tid; i < NBCE; i += 256) s += aload(&bceA[i]);  // 1024
  float bce_sum = block_reduce_256(s, smr, tid);

  s = 0.f;
  for (int i = tid; i < NWORK; i += 256) s += aload(&chain_p[i]);  // 6656
  float hd_sum = block_reduce_256(s, smr, tid);

  {
    int img = tid >> 4, part = tid & 15;  // 16 threads per image
    float sp = 0.f, st = 0.f, spt = 0.f;
    for (int j = part; j < 64; j += 16) {  // 64 partials/image, 4 iters
      int idx = img * 64 + j;
      sp += aload(&spA[idx]);
      st += aload(&stA[idx]);
      spt += aload(&sptA[idx]);
    }
#pragma unroll
    for (int off = 8; off > 0; off >>= 1) {
      sp += __shfl_down(sp, off, 16);
      st += __shfl_down(st, off, 16);
      spt += __shfl_down(spt, off, 16);
    }
    if (part == 0) {
      smImg[img][0] = sp;
      smImg[img][1] = st;
      smImg[img][2] = spt;
    }
  }
  __syncthreads();
  if (tid < 16) {
    double sp = smImg[tid][0], st = smImg[tid][1], spt = smImg[tid][2];
    double dice = (2.0 * spt + 1e-6) / (sp + st + 1e-6 + 1e-7);
    double tv = (spt + 1e-6) /
                (spt + 0.7 * (sp - spt) + 0.3 * (st - spt) + 1e-6 + 1e-7);
    smd[tid][0] = 1.0 - dice;
    // x^0.75 = sqrt(x)*sqrt(sqrt(x)): avoids libm pow in this kernel
    // (register-pressure hazard); R9 proved absmax 0.0 with this form.
    float xs = (float)(1.0 - tv);
    smd[tid][1] = (double)(sqrtf(xs) * sqrtf(sqrtf(xs)));
  }
  __syncthreads();
  if (tid == 0) {
    double dice_l = 0.0, ft_l = 0.0;
    for (int i = 0; i < 16; ++i) {
      dice_l += smd[i][0];
      ft_l += smd[i][1];
    }
    dice_l /= 16.0;
    ft_l /= 16.0;
    const double Nd = (double)Nc;
    double bce = (double)bce_sum / Nd;
    double hd = ((double)hd_sum / Nd) / (5.5 + 1e-8);
    out[0] = (float)(bce + dice_l + ft_l + 0.1 * hd);
  }
}

// ---------------- merged kernel ---------------------------------------------
// R7's proven block mix (BCE first, stencil backfills) + last-block-done tail.
// Visibility protocol: each wave's agent-scope slot store is drained by the
// tail __syncthreads (vmcnt(0) before s_barrier); the ACQ_REL counter RMW
// publishes; the last block reads slots with agent-scope loads (bypass stale
// local L2). Slots are written exactly once per launch before the counter
// increments -> no zeroing of slots needed, only the counter.
// __launch_bounds__(256, 4): the ONLY proven shape (R5/R8: else spill).
__global__ void __launch_bounds__(256, 4) fused_kernel(
    const float* __restrict__ logits, const int* __restrict__ target,
    float* __restrict__ bceA, float* __restrict__ spA,
    float* __restrict__ stA, float* __restrict__ sptA,
    float* __restrict__ chain_p, unsigned* __restrict__ counter,
    float* __restrict__ out) {
  __shared__ float smr[4];
  __shared__ float smImg[16][3];
  __shared__ double smd[16][2];
  __shared__ unsigned s_old;
  int tid = threadIdx.x;

  if (blockIdx.x < NBCE) {
    bce_body(logits, target, blockIdx.x, bceA, spA, stA, sptA, smr);
  } else {
    int lane = tid & 63;
    int wv = __builtin_amdgcn_readfirstlane(tid >> 6);
    int widx = (blockIdx.x - NBCE) * 4 + wv;  // 0..6655, exact
    int strip = widx % NSTRIP;
    int rest = widx / NSTRIP;
    int band = rest & 15;
    int bz = rest >> 4;  // 0..31
    int img = bz & 15, chain = bz >> 4;
    const float* Lg = logits + (size_t)img * HWc;
    const int* Tg = target + (size_t)img * HWc;
    if (chain == 0)
      fused_body<0>(Lg, Tg, lane, strip, band, widx, chain_p);
    else
      fused_body<1>(Lg, Tg, lane, strip, band, widx, chain_p);
  }

  // ---- done-counting tail: one integer RMW per block (2688 total).
  __syncthreads();  // drains every wave's slot store (vmcnt(0) + barrier)
  if (tid == 0) {
    s_old = __hip_atomic_fetch_add(counter, 1u, __ATOMIC_ACQ_REL,
                                   __HIP_MEMORY_SCOPE_AGENT);
  }
  __syncthreads();
  if (s_old == (unsigned)(NBLOCKS - 1))
    combine(bceA, spA, stA, sptA, chain_p, out, smr, smImg, smd, tid);
}

}  // namespace

extern "C" void kernel_launch(void* const* d_in, const int* in_sizes, int n_in,
                              void* d_out, int out_size, void* d_ws,
                              size_t ws_size, hipStream_t stream) {
  const float* logits = (const float*)d_in[0];
  const int* target = (const int*)d_in[1];
  float* out = (float*)d_out;

  float* part = (float*)d_ws;
  float* bceA = part;                        // 1024
  float* spA = part + NBCE;                  // 1024
  float* stA = part + 2 * NBCE;              // 1024
  float* sptA = part + 3 * NBCE;             // 1024
  float* chain_p = part + 4 * NBCE;          // 6656
  unsigned* counter = (unsigned*)(part + 4 * NBCE + NWORK);

  // Zero only the done-counter (slots are written-before-read every launch).
  hipMemsetAsync(counter, 0, sizeof(unsigned), stream);

  fused_kernel<<<dim3(NBLOCKS), dim3(256), 0, stream>>>(
      logits, target, bceA, spA, stA, sptA, chain_p, counter, out);
}

// Round 11
// 149.684 us; speedup vs baseline: 2.5541x; 1.2022x over previous
//
#include <hip/hip_runtime.h>
#include <math.h>

namespace {

constexpr int B = 16, H = 512, W = 512;
constexpr int HWc = H * W;                 // 262144
constexpr size_t Nc = (size_t)B * HWc;     // 4194304

// Strip geometry: 64-lane wave holds cols [strip*42-11, strip*42+52].
// Boundary stencil (3x3) corrupts lanes 0,63; each of the 10 dilation steps
// corrupts one more lane per side -> valid central lanes 11..52 = 42 cols.
// 13 strips x 42 = 546 >= 512 (mask col < 512). Exact tiling, no overlap.
constexpr int NSTRIP = 13;
constexpr int CENT = 42;
constexpr int NBAND = 16;  // 512 / 32 rows
constexpr int NWORK = NSTRIP * NBAND * B * 2;  // 6656 wave work items
constexpr int NSB = NWORK / 4;                 // 1664 stencil blocks
constexpr int NBCE = B * 64;                   // 1024 bce blocks
constexpr int NBLOCKS = NSB + NBCE;            // 2688

// R10 post-mortem: replacing contended fp RMWs with distinct-address stores
// did NOT remove the +50us stall -> contention wasn't the cause. R9/R10's
// shared feature vs R7: a per-block DEVICE-SCOPE FENCE (R9 __threadfence,
// R10 ACQ_REL atomic). On gfx950 device-scope acquire lowers to buffer_inv =
// full-L2 invalidate; 2688 of them continuously wipe all 8 XCD L2s, turning
// every L2 hit into an L3 hit (FETCH unchanged, latency 2x, VALUBusy 75->43).
// Fix: RELAXED counter (no cache maintenance ops). Visibility is structural:
// slot stores are agent-scope write-through (never parked in non-coherent
// L2), drained by the tail __syncthreads (vmcnt(0)) BEFORE the counter RMW
// issues; the last block reads slots with agent-scope loads that bypass its
// local L2. This read/write path is exactly what R9/R10 already verified
// (absmax 0.0) -- only the ordering decoration changes.
__device__ __forceinline__ void astore(float* p, float v) {
  __hip_atomic_store(p, v, __ATOMIC_RELAXED, __HIP_MEMORY_SCOPE_AGENT);
}
__device__ __forceinline__ float aload(const float* p) {
  return __hip_atomic_load(p, __ATOMIC_RELAXED, __HIP_MEMORY_SCOPE_AGENT);
}

// ---------------- DPP lane shifts ----------------
// wave_shr:1 (0x138): lane i <- lane i-1 (lane 0 keeps own -> replicate edge)
// wave_shl:1 (0x130): lane i <- lane i+1 (lane 63 keeps own)
template <int CTRL>
__device__ __forceinline__ float dpp_shift1(float v) {
  int i = __float_as_int(v);
  int r = __builtin_amdgcn_update_dpp(i, i, CTRL, 0xF, 0xF, false);
  return __int_as_float(r);
}

// R5: NO inline-asm max3 (pins live set to VGPR half -> spill). R8: NO
// __launch_bounds__ loosening ((256,3) chose spill over AGPR split).
__device__ __forceinline__ float hmax3(float v) {
  return fmaxf(fmaxf(dpp_shift1<0x138>(v), v), dpp_shift1<0x130>(v));
}
__device__ __forceinline__ void hminmax3(float v, float& mx, float& mn) {
  float s1 = dpp_shift1<0x138>(v);
  float s2 = dpp_shift1<0x130>(v);
  mx = fmaxf(fmaxf(s1, v), s2);
  mn = fminf(fminf(s1, v), s2);
}

__device__ __forceinline__ float wave_sum(float v) {
#pragma unroll
  for (int off = 32; off > 0; off >>= 1) v += __shfl_down(v, off);
  return v;
}

// --- block-wide sum over 256 threads (4 waves of 64). Valid on tid==0 only.
__device__ __forceinline__ float block_reduce_256(float v, float* sm, int tid) {
#pragma unroll
  for (int off = 32; off > 0; off >>= 1) v += __shfl_down(v, off);
  int lane = tid & 63, wid = tid >> 6;
  if (lane == 0) sm[wid] = v;
  __syncthreads();
  float r = 0.f;
  if (tid == 0) r = sm[0] + sm[1] + sm[2] + sm[3];
  __syncthreads();
  return r;
}

// CH==0: src map = sigmoid(logits), oth map = target.
// CH==1: src map = target,          oth map = sigmoid(logits).
template <int CH>
__device__ __forceinline__ float load_src(const float* __restrict__ Lg,
                                          const int* __restrict__ Tg, int gy,
                                          int colc) {
  gy = min(max(gy, 0), H - 1);  // wave-uniform clamp
  if constexpr (CH == 0) {
    float x = Lg[gy * W + colc];
    float e = __expf(-x);
    return __builtin_amdgcn_rcpf(1.f + e);
  } else {
    return (float)Tg[gy * W + colc];
  }
}

// ---- dilation steps via template recursion (R2: compile-time D keeps all
// indices constant -> arrays stay register-resident).
// R4: accv[4] -- single acc was a 320-deep dependent FMA chain.
template <int D>
__device__ __forceinline__ void dilate_steps(float (&a)[52],
                                             const float (&o)[32],
                                             float (&accv)[4]) {
  if constexpr (D <= 10) {
    float hp = hmax3(a[D - 1]);
    float hc = hmax3(a[D]);
#pragma unroll
    for (int r = D; r <= 51 - D; ++r) {  // trip count 52-2D: compile-time
      float hn = hmax3(a[r + 1]);
      float nv = fmaxf(fmaxf(hp, hc), hn);
      hp = hc;
      hc = hn;
      a[r] = nv;
    }
    constexpr float wd = 0.1f * (float)D;
#pragma unroll
    for (int k = 0; k < 32; ++k) accv[k & 3] += wd * fabsf(a[10 + k] - o[k]);
    dilate_steps<D + 1>(a, o, accv);
  }
}

// ---------------- stencil wave body (R7-proven) -----------------------------
template <int CH>
__device__ __forceinline__ void fused_body(const float* __restrict__ Lg,
                                           const int* __restrict__ Tg,
                                           int lane, int strip, int band,
                                           int widx,
                                           float* __restrict__ chain_p) {
  int col = strip * CENT - 11 + lane;
  int colc = min(max(col, 0), W - 1);
  int y0 = band * 32;

  // ---- other-map boundary, central rows y0..y0+31 (rolling 3-row stencil)
  float o[32];
  {
    float v0 = load_src<1 - CH>(Lg, Tg, y0 - 1, colc);
    float v1 = load_src<1 - CH>(Lg, Tg, y0, colc);
    float hx0, hn0, hx1, hn1;
    hminmax3(v0, hx0, hn0);
    hminmax3(v1, hx1, hn1);
#pragma unroll
    for (int k = 0; k < 32; ++k) {
      float v2 = load_src<1 - CH>(Lg, Tg, y0 + 1 + k, colc);
      float hx2, hn2;
      hminmax3(v2, hx2, hn2);
      o[k] = fmaxf(fmaxf(hx0, hx1), hx2) - fminf(fminf(hn0, hn1), hn2);
      hx0 = hx1;
      hx1 = hx2;
      hn0 = hn1;
      hn1 = hn2;
    }
  }

  // ---- src-map boundary incl. vertical halo: rows y0-10 .. y0+41
  float a[52];
  {
    float v0 = load_src<CH>(Lg, Tg, y0 - 11, colc);
    float v1 = load_src<CH>(Lg, Tg, y0 - 10, colc);
    float hx0, hn0, hx1, hn1;
    hminmax3(v0, hx0, hn0);
    hminmax3(v1, hx1, hn1);
#pragma unroll
    for (int r = 0; r < 52; ++r) {
      float v2 = load_src<CH>(Lg, Tg, y0 - 9 + r, colc);
      float hx2, hn2;
      hminmax3(v2, hx2, hn2);
      a[r] = fmaxf(fmaxf(hx0, hx1), hx2) - fminf(fminf(hn0, hn1), hn2);
      hx0 = hx1;
      hx1 = hx2;
      hn0 = hn1;
      hn1 = hn2;
    }
  }

  // ---- 10-step register-resident dilation + weighted L1 accumulation
  float accv[4] = {0.f, 0.f, 0.f, 0.f};
  dilate_steps<1>(a, o, accv);
  float acc = (accv[0] + accv[1]) + (accv[2] + accv[3]);

  bool valid = (lane >= 11 && lane <= 52 && col < W);
  acc = valid ? acc : 0.f;
  acc = wave_sum(acc);
  if (lane == 0) astore(&chain_p[widx], acc);  // distinct addr: no contention
}

// ---------------- BCE block body --------------------------------------------
// Identity: max(x,0) - x*t + log1p(exp(-|x|)) == x*(1-t) + log(1+e^-x).
__device__ __forceinline__ void bce_body(const float* __restrict__ logits,
                                         const int* __restrict__ target,
                                         int blk, float* __restrict__ bceA,
                                         float* __restrict__ spA,
                                         float* __restrict__ stA,
                                         float* __restrict__ sptA, float* sm) {
  int img = blk >> 6, seg = blk & 63;  // 64 blocks/image
  const float4* L4 =
      (const float4*)(logits + (size_t)img * HWc + (size_t)seg * 4096);
  const int4* T4 =
      (const int4*)(target + (size_t)img * HWc + (size_t)seg * 4096);
  int tid = threadIdx.x;
  float s_bce = 0.f, s_p = 0.f, s_t = 0.f, s_pt = 0.f;
#pragma unroll
  for (int it = 0; it < 4; ++it) {
    float4 x4 = L4[it * 256 + tid];
    int4 t4 = T4[it * 256 + tid];
    float xs[4] = {x4.x, x4.y, x4.z, x4.w};
    int ts[4] = {t4.x, t4.y, t4.z, t4.w};
#pragma unroll
    for (int j = 0; j < 4; ++j) {
      float x = xs[j];
      float tf = (float)ts[j];
      float e = __expf(-x);
      float p = __builtin_amdgcn_rcpf(1.f + e);
      s_p += p;
      s_t += tf;
      s_pt += p * tf;
      s_bce += x * (1.f - tf) + __logf(1.f + e);
    }
  }
  float r;
  r = block_reduce_256(s_bce, sm, tid);
  if (tid == 0) astore(&bceA[blk], r);
  r = block_reduce_256(s_p, sm, tid);
  if (tid == 0) astore(&spA[blk], r);
  r = block_reduce_256(s_t, sm, tid);
  if (tid == 0) astore(&stA[blk], r);
  r = block_reduce_256(s_pt, sm, tid);
  if (tid == 0) astore(&sptA[blk], r);
}

// ---------------- last-block combine (all 256 threads; R7 finalize logic) ---
__device__ __forceinline__ void combine(
    const float* __restrict__ bceA, const float* __restrict__ spA,
    const float* __restrict__ stA, const float* __restrict__ sptA,
    const float* __restrict__ chain_p, float* __restrict__ out, float* smr,
    float (*smImg)[3], double (*smd)[2], int tid) {
  float s = 0.f;
  for (int i = tid; i < NBCE; i += 256) s += aload(&bceA[i]);  // 1024
  float bce_sum = block_reduce_256(s, smr, tid);

  s = 0.f;
  for (int i = tid; i < NWORK; i += 256) s += aload(&chain_p[i]);  // 6656
  float hd_sum = block_reduce_256(s, smr, tid);

  {
    int img = tid >> 4, part = tid & 15;  // 16 threads per image
    float sp = 0.f, st = 0.f, spt = 0.f;
    for (int j = part; j < 64; j += 16) {  // 64 partials/image, 4 iters
      int idx = img * 64 + j;
      sp += aload(&spA[idx]);
      st += aload(&stA[idx]);
      spt += aload(&sptA[idx]);
    }
#pragma unroll
    for (int off = 8; off > 0; off >>= 1) {
      sp += __shfl_down(sp, off, 16);
      st += __shfl_down(st, off, 16);
      spt += __shfl_down(spt, off, 16);
    }
    if (part == 0) {
      smImg[img][0] = sp;
      smImg[img][1] = st;
      smImg[img][2] = spt;
    }
  }
  __syncthreads();
  if (tid < 16) {
    double sp = smImg[tid][0], st = smImg[tid][1], spt = smImg[tid][2];
    double dice = (2.0 * spt + 1e-6) / (sp + st + 1e-6 + 1e-7);
    double tv = (spt + 1e-6) /
                (spt + 0.7 * (sp - spt) + 0.3 * (st - spt) + 1e-6 + 1e-7);
    smd[tid][0] = 1.0 - dice;
    // x^0.75 = sqrt(x)*sqrt(sqrt(x)): avoids libm pow in this kernel
    // (register-pressure hazard); R9/R10 proved absmax 0.0 with this form.
    float xs = (float)(1.0 - tv);
    smd[tid][1] = (double)(sqrtf(xs) * sqrtf(sqrtf(xs)));
  }
  __syncthreads();
  if (tid == 0) {
    double dice_l = 0.0, ft_l = 0.0;
    for (int i = 0; i < 16; ++i) {
      dice_l += smd[i][0];
      ft_l += smd[i][1];
    }
    dice_l /= 16.0;
    ft_l /= 16.0;
    const double Nd = (double)Nc;
    double bce = (double)bce_sum / Nd;
    double hd = ((double)hd_sum / Nd) / (5.5 + 1e-8);
    out[0] = (float)(bce + dice_l + ft_l + 0.1 * hd);
  }
}

// ---------------- merged kernel ---------------------------------------------
// R7's proven block mix (BCE first, stencil backfills) + last-block-done tail
// with a RELAXED counter (no buffer_inv/buffer_wbl2 -> no L2 wipe).
// __launch_bounds__(256, 4): the ONLY proven shape (R5/R8: else spill).
__global__ void __launch_bounds__(256, 4) fused_kernel(
    const float* __restrict__ logits, const int* __restrict__ target,
    float* __restrict__ bceA, float* __restrict__ spA,
    float* __restrict__ stA, float* __restrict__ sptA,
    float* __restrict__ chain_p, unsigned* __restrict__ counter,
    float* __restrict__ out) {
  __shared__ float smr[4];
  __shared__ float smImg[16][3];
  __shared__ double smd[16][2];
  __shared__ unsigned s_old;
  int tid = threadIdx.x;

  if (blockIdx.x < NBCE) {
    bce_body(logits, target, blockIdx.x, bceA, spA, stA, sptA, smr);
  } else {
    int lane = tid & 63;
    int wv = __builtin_amdgcn_readfirstlane(tid >> 6);
    int widx = (blockIdx.x - NBCE) * 4 + wv;  // 0..6655, exact
    int strip = widx % NSTRIP;
    int rest = widx / NSTRIP;
    int band = rest & 15;
    int bz = rest >> 4;  // 0..31
    int img = bz & 15, chain = bz >> 4;
    const float* Lg = logits + (size_t)img * HWc;
    const int* Tg = target + (size_t)img * HWc;
    if (chain == 0)
      fused_body<0>(Lg, Tg, lane, strip, band, widx, chain_p);
    else
      fused_body<1>(Lg, Tg, lane, strip, band, widx, chain_p);
  }

  // ---- done-counting tail: one RELAXED integer RMW per block. The
  // __syncthreads drains every wave's agent-scope slot store (vmcnt(0)
  // before s_barrier) so the stores are globally performed before tid0's
  // counter RMW can issue. No fences -> no L2 invalidations.
  __syncthreads();
  if (tid == 0) {
    s_old = __hip_atomic_fetch_add(counter, 1u, __ATOMIC_RELAXED,
                                   __HIP_MEMORY_SCOPE_AGENT);
  }
  __syncthreads();
  if (s_old == (unsigned)(NBLOCKS - 1))
    combine(bceA, spA, stA, sptA, chain_p, out, smr, smImg, smd, tid);
}

}  // namespace

extern "C" void kernel_launch(void* const* d_in, const int* in_sizes, int n_in,
                              void* d_out, int out_size, void* d_ws,
                              size_t ws_size, hipStream_t stream) {
  const float* logits = (const float*)d_in[0];
  const int* target = (const int*)d_in[1];
  float* out = (float*)d_out;

  float* part = (float*)d_ws;
  float* bceA = part;                        // 1024
  float* spA = part + NBCE;                  // 1024
  float* stA = part + 2 * NBCE;              // 1024
  float* sptA = part + 3 * NBCE;             // 1024
  float* chain_p = part + 4 * NBCE;          // 6656
  unsigned* counter = (unsigned*)(part + 4 * NBCE + NWORK);

  // Zero only the done-counter (slots are written-before-read every launch).
  hipMemsetAsync(counter, 0, sizeof(unsigned), stream);

  fused_kernel<<<dim3(NBLOCKS), dim3(256), 0, stream>>>(
      logits, target, bceA, spA, stA, sptA, chain_p, counter, out);
}

// Round 12
// 119.374 us; speedup vs baseline: 3.2026x; 1.2539x over previous
//
#include <hip/hip_runtime.h>
#include <math.h>

namespace {

constexpr int B = 16, H = 512, W = 512;
constexpr int HWc = H * W;                 // 262144
constexpr size_t Nc = (size_t)B * HWc;     // 4194304

// Strip geometry: 64-lane wave holds cols [strip*42-11, strip*42+52].
// Boundary stencil (3x3) corrupts lanes 0,63; each of the 10 dilation steps
// corrupts one more lane per side -> valid central lanes 11..52 = 42 cols.
// 13 strips x 42 = 546 >= 512 (mask col < 512). Exact tiling, no overlap.
constexpr int NSTRIP = 13;
constexpr int CENT = 42;
constexpr int NBAND = 16;  // 512 / 32 rows
constexpr int NWORK = NSTRIP * NBAND * B * 2;  // 6656 wave work items
constexpr int NSB = NWORK / 4;                 // 1664 stencil blocks
constexpr int NBCE = B * 64;                   // 1024 bce blocks

// R9-R11 post-mortem: every single-kernel last-block-done variant (fp RMW +
// threadfence 180us; agent stores + ACQ_REL 180us; RELAXED counter 150us)
// lost to R7's plain two-kernel structure (136.6us). The tail sync pattern
// is abandoned; this file is R7's exact structure + a bitwise chain-1.

// ---------------- DPP lane shifts ----------------
// wave_shr:1 (0x138): lane i <- lane i-1 (lane 0 keeps own -> replicate edge)
// wave_shl:1 (0x130): lane i <- lane i+1 (lane 63 keeps own)
template <int CTRL>
__device__ __forceinline__ float dpp_shift1(float v) {
  int i = __float_as_int(v);
  int r = __builtin_amdgcn_update_dpp(i, i, CTRL, 0xF, 0xF, false);
  return __int_as_float(r);
}
template <int CTRL>
__device__ __forceinline__ unsigned dpp_shift1u(unsigned v) {
  return (unsigned)__builtin_amdgcn_update_dpp((int)v, (int)v, CTRL, 0xF, 0xF,
                                               false);
}

// R5: NO inline-asm max3 (pins live set to VGPR half -> spill). R8: NO
// __launch_bounds__ loosening ((256,3) chose spill over AGPR split).
__device__ __forceinline__ float hmax3(float v) {
  return fmaxf(fmaxf(dpp_shift1<0x138>(v), v), dpp_shift1<0x130>(v));
}
__device__ __forceinline__ void hminmax3(float v, float& mx, float& mn) {
  float s1 = dpp_shift1<0x138>(v);
  float s2 = dpp_shift1<0x130>(v);
  mx = fmaxf(fmaxf(s1, v), s2);
  mn = fminf(fminf(s1, v), s2);
}

// Bitwise horizontal 3-lane OR/AND on a packed-rows u64 (per-32b half; the
// DPP moves whole packed columns across lanes, replicating at wave edges --
// identical halo geometry to the float hmax3/hmin3 path).
__device__ __forceinline__ unsigned long long or3_lanes(unsigned long long v) {
  unsigned lo = (unsigned)v, hi = (unsigned)(v >> 32);
  unsigned rlo = dpp_shift1u<0x138>(lo) | lo | dpp_shift1u<0x130>(lo);
  unsigned rhi = dpp_shift1u<0x138>(hi) | hi | dpp_shift1u<0x130>(hi);
  return ((unsigned long long)rhi << 32) | rlo;
}
__device__ __forceinline__ unsigned long long and3_lanes(unsigned long long v) {
  unsigned lo = (unsigned)v, hi = (unsigned)(v >> 32);
  unsigned rlo = dpp_shift1u<0x138>(lo) & lo & dpp_shift1u<0x130>(lo);
  unsigned rhi = dpp_shift1u<0x138>(hi) & hi & dpp_shift1u<0x130>(hi);
  return ((unsigned long long)rhi << 32) | rlo;
}

__device__ __forceinline__ float wave_sum(float v) {
#pragma unroll
  for (int off = 32; off > 0; off >>= 1) v += __shfl_down(v, off);
  return v;
}

// --- block-wide sum over 256 threads (4 waves of 64). Valid on tid==0 only.
__device__ __forceinline__ float block_reduce_256(float v, float* sm, int tid) {
#pragma unroll
  for (int off = 32; off > 0; off >>= 1) v += __shfl_down(v, off);
  int lane = tid & 63, wid = tid >> 6;
  if (lane == 0) sm[wid] = v;
  __syncthreads();
  float r = 0.f;
  if (tid == 0) r = sm[0] + sm[1] + sm[2] + sm[3];
  __syncthreads();
  return r;
}

// CH==0: src map = sigmoid(logits), oth map = target.
// CH==1: src map = target,          oth map = sigmoid(logits).
template <int CH>
__device__ __forceinline__ float load_src(const float* __restrict__ Lg,
                                          const int* __restrict__ Tg, int gy,
                                          int colc) {
  gy = min(max(gy, 0), H - 1);  // wave-uniform clamp
  if constexpr (CH == 0) {
    float x = Lg[gy * W + colc];
    float e = __expf(-x);
    return __builtin_amdgcn_rcpf(1.f + e);
  } else {
    return (float)Tg[gy * W + colc];
  }
}

// ---- dilation steps via template recursion (R2: compile-time D keeps all
// indices constant -> arrays stay register-resident).
// R4: accv[4] -- single acc was a 320-deep dependent FMA chain.
template <int D>
__device__ __forceinline__ void dilate_steps(float (&a)[52],
                                             const float (&o)[32],
                                             float (&accv)[4]) {
  if constexpr (D <= 10) {
    float hp = hmax3(a[D - 1]);
    float hc = hmax3(a[D]);
#pragma unroll
    for (int r = D; r <= 51 - D; ++r) {  // trip count 52-2D: compile-time
      float hn = hmax3(a[r + 1]);
      float nv = fmaxf(fmaxf(hp, hc), hn);
      hp = hc;
      hc = hn;
      a[r] = nv;
    }
    constexpr float wd = 0.1f * (float)D;
#pragma unroll
    for (int k = 0; k < 32; ++k) accv[k & 3] += wd * fabsf(a[10 + k] - o[k]);
    dilate_steps<D + 1>(a, o, accv);
  }
}

// ---------------- chain-0 wave body (R7-proven, untouched) ------------------
// src = sigmoid(logits) (continuous -> float DPP cascade), oth = target.
__device__ __forceinline__ void fused_body0(const float* __restrict__ Lg,
                                            const int* __restrict__ Tg,
                                            int lane, int strip, int band,
                                            int bz,
                                            float* __restrict__ chain_p) {
  int col = strip * CENT - 11 + lane;
  int colc = min(max(col, 0), W - 1);
  int y0 = band * 32;

  // ---- other-map boundary (target), central rows y0..y0+31
  float o[32];
  {
    float v0 = load_src<1>(Lg, Tg, y0 - 1, colc);
    float v1 = load_src<1>(Lg, Tg, y0, colc);
    float hx0, hn0, hx1, hn1;
    hminmax3(v0, hx0, hn0);
    hminmax3(v1, hx1, hn1);
#pragma unroll
    for (int k = 0; k < 32; ++k) {
      float v2 = load_src<1>(Lg, Tg, y0 + 1 + k, colc);
      float hx2, hn2;
      hminmax3(v2, hx2, hn2);
      o[k] = fmaxf(fmaxf(hx0, hx1), hx2) - fminf(fminf(hn0, hn1), hn2);
      hx0 = hx1;
      hx1 = hx2;
      hn0 = hn1;
      hn1 = hn2;
    }
  }

  // ---- src-map boundary incl. vertical halo: rows y0-10 .. y0+41
  float a[52];
  {
    float v0 = load_src<0>(Lg, Tg, y0 - 11, colc);
    float v1 = load_src<0>(Lg, Tg, y0 - 10, colc);
    float hx0, hn0, hx1, hn1;
    hminmax3(v0, hx0, hn0);
    hminmax3(v1, hx1, hn1);
#pragma unroll
    for (int r = 0; r < 52; ++r) {
      float v2 = load_src<0>(Lg, Tg, y0 - 9 + r, colc);
      float hx2, hn2;
      hminmax3(v2, hx2, hn2);
      a[r] = fmaxf(fmaxf(hx0, hx1), hx2) - fminf(fminf(hn0, hn1), hn2);
      hx0 = hx1;
      hx1 = hx2;
      hn0 = hn1;
      hn1 = hn2;
    }
  }

  float accv[4] = {0.f, 0.f, 0.f, 0.f};
  dilate_steps<1>(a, o, accv);
  float acc = (accv[0] + accv[1]) + (accv[2] + accv[3]);

  bool valid = (lane >= 11 && lane <= 52 && col < W);
  acc = valid ? acc : 0.f;
  acc = wave_sum(acc);
  if (lane == 0) chain_p[(bz * NBAND + band) * NSTRIP + strip] = acc;
}

// ---------------- chain-1 wave body: BITWISE cascade ------------------------
// src = target (binary!): max of bits = OR, min = AND. Lane packs its
// column's 54 window rows (y0-11..y0+42) into one u64 (bit j = row y0-11+j).
// Vertical 3-row max/min = shift-OR/AND on the whole register (32 rows per
// instr vs per-row max3); horizontal = DPP-OR across lanes. The 10-step
// cascade: ~140 instr vs ~2.5k float. Bit-exact with the float path (values
// are exactly 0.0/1.0 in both).
// Validity: boundary bit j valid for j=1..52 (after >>1: rows 0..51); step d
// output row r valid for r in [d, 51-d], reads prev rows r-1..r+1 all valid
// -- shifted-in garbage never propagates into [10,41], same as float halo.
__device__ __forceinline__ void fused_body1(const float* __restrict__ Lg,
                                            const int* __restrict__ Tg,
                                            int lane, int strip, int band,
                                            int bz,
                                            float* __restrict__ chain_p) {
  int col = strip * CENT - 11 + lane;
  int colc = min(max(col, 0), W - 1);
  int y0 = band * 32;

  // ---- other-map boundary (sigmoid of logits), central rows y0..y0+31
  float o[32];
  {
    float v0 = load_src<0>(Lg, Tg, y0 - 1, colc);
    float v1 = load_src<0>(Lg, Tg, y0, colc);
    float hx0, hn0, hx1, hn1;
    hminmax3(v0, hx0, hn0);
    hminmax3(v1, hx1, hn1);
#pragma unroll
    for (int k = 0; k < 32; ++k) {
      float v2 = load_src<0>(Lg, Tg, y0 + 1 + k, colc);
      float hx2, hn2;
      hminmax3(v2, hx2, hn2);
      o[k] = fmaxf(fmaxf(hx0, hx1), hx2) - fminf(fminf(hn0, hn1), hn2);
      hx0 = hx1;
      hx1 = hx2;
      hn0 = hn1;
      hn1 = hn2;
    }
  }

  // ---- pack 54 target rows into bits (clamped rows inherit replicate edge)
  unsigned long long tb = 0ull;
#pragma unroll
  for (int j = 0; j < 54; ++j) {
    int gy = min(max(y0 - 11 + j, 0), H - 1);
    tb |= (unsigned long long)(unsigned)Tg[gy * W + colc] << j;
  }

  // ---- 3x3 boundary: dil & ~ero; align so bit r = boundary at row y0-10+r
  unsigned long long vd = tb | (tb << 1) | (tb >> 1);
  unsigned long long ve = tb & (tb << 1) & (tb >> 1);
  unsigned long long ab = (or3_lanes(vd) & ~and3_lanes(ve)) >> 1;

  // ---- 10-step bitwise dilation + weighted L1 accumulation
  float accv[4] = {0.f, 0.f, 0.f, 0.f};
#pragma unroll
  for (int d = 1; d <= 10; ++d) {
    unsigned long long s = ab | (ab << 1) | (ab >> 1);
    ab = or3_lanes(s);
    const float wd = 0.1f * (float)d;
    unsigned lo = (unsigned)ab, hi = (unsigned)(ab >> 32);
#pragma unroll
    for (int k = 0; k < 32; ++k) {
      // row 10+k: bits 10..31 in lo (k<22), bits 0..9 in hi (k>=22)
      unsigned bit =
          (k < 22) ? ((lo >> (10 + k)) & 1u) : ((hi >> (k - 22)) & 1u);
      accv[k & 3] += wd * fabsf((float)bit - o[k]);
    }
  }
  float acc = (accv[0] + accv[1]) + (accv[2] + accv[3]);

  bool valid = (lane >= 11 && lane <= 52 && col < W);
  acc = valid ? acc : 0.f;
  acc = wave_sum(acc);
  if (lane == 0) chain_p[(bz * NBAND + band) * NSTRIP + strip] = acc;
}

// ---------------- BCE block body (R7-proven) --------------------------------
// Identity: max(x,0) - x*t + log1p(exp(-|x|)) == x*(1-t) + log(1+e^-x).
__device__ __forceinline__ void bce_body(const float* __restrict__ logits,
                                         const int* __restrict__ target,
                                         int blk, float* __restrict__ bceA,
                                         float* __restrict__ spA,
                                         float* __restrict__ stA,
                                         float* __restrict__ sptA, float* sm) {
  int img = blk >> 6, seg = blk & 63;  // 64 blocks/image
  const float4* L4 =
      (const float4*)(logits + (size_t)img * HWc + (size_t)seg * 4096);
  const int4* T4 =
      (const int4*)(target + (size_t)img * HWc + (size_t)seg * 4096);
  int tid = threadIdx.x;
  float s_bce = 0.f, s_p = 0.f, s_t = 0.f, s_pt = 0.f;
#pragma unroll
  for (int it = 0; it < 4; ++it) {
    float4 x4 = L4[it * 256 + tid];
    int4 t4 = T4[it * 256 + tid];
    float xs[4] = {x4.x, x4.y, x4.z, x4.w};
    int ts[4] = {t4.x, t4.y, t4.z, t4.w};
#pragma unroll
    for (int j = 0; j < 4; ++j) {
      float x = xs[j];
      float tf = (float)ts[j];
      float e = __expf(-x);
      float p = __builtin_amdgcn_rcpf(1.f + e);
      s_p += p;
      s_t += tf;
      s_pt += p * tf;
      s_bce += x * (1.f - tf) + __logf(1.f + e);
    }
  }
  float r;
  r = block_reduce_256(s_bce, sm, tid);
  if (tid == 0) bceA[blk] = r;
  r = block_reduce_256(s_p, sm, tid);
  if (tid == 0) spA[blk] = r;
  r = block_reduce_256(s_t, sm, tid);
  if (tid == 0) stA[blk] = r;
  r = block_reduce_256(s_pt, sm, tid);
  if (tid == 0) sptA[blk] = r;
}

// ---------------- merged kernel (R7-proven structure) -----------------------
// Heterogeneous blocks: first NBCE blocks stream BCE/dice partials (memory-
// bound), remaining NSB blocks run the stencil (VALU-bound), 4 independent
// waves each. __launch_bounds__(256, 4): the ONLY proven shape.
__global__ void __launch_bounds__(256, 4) fused_kernel(
    const float* __restrict__ logits, const int* __restrict__ target,
    float* __restrict__ bceA, float* __restrict__ spA,
    float* __restrict__ stA, float* __restrict__ sptA,
    float* __restrict__ chain_p) {
  __shared__ float smr[4];
  int tid = threadIdx.x;
  if (blockIdx.x < NBCE) {
    bce_body(logits, target, blockIdx.x, bceA, spA, stA, sptA, smr);
    return;
  }
  int lane = tid & 63;
  int wv = __builtin_amdgcn_readfirstlane(tid >> 6);
  int widx = (blockIdx.x - NBCE) * 4 + wv;  // 0..6655, exact
  int strip = widx % NSTRIP;
  int rest = widx / NSTRIP;
  int band = rest & 15;
  int bz = rest >> 4;  // 0..31
  int img = bz & 15, chain = bz >> 4;
  const float* Lg = logits + (size_t)img * HWc;
  const int* Tg = target + (size_t)img * HWc;
  if (chain == 0)
    fused_body0(Lg, Tg, lane, strip, band, bz, chain_p);
  else
    fused_body1(Lg, Tg, lane, strip, band, bz, chain_p);
}

// ---------------- finalize (R7 + float4 sum loops) --------------------------
__global__ void finalize_kernel(const float* __restrict__ bceA,
                                const float* __restrict__ spA,
                                const float* __restrict__ stA,
                                const float* __restrict__ sptA,
                                const float* __restrict__ chain_p,
                                float* __restrict__ out) {
  __shared__ float smr[4];
  __shared__ float smImg[16][3];
  __shared__ double smd[16][2];
  int tid = threadIdx.x;

  float s = 0.f;
  {
    const float4* b4 = (const float4*)bceA;  // 256 float4s
    for (int i = tid; i < NBCE / 4; i += 256) {
      float4 v = b4[i];
      s += (v.x + v.y) + (v.z + v.w);
    }
  }
  float bce_sum = block_reduce_256(s, smr, tid);

  s = 0.f;
  {
    const float4* c4 = (const float4*)chain_p;  // 1664 float4s
    for (int i = tid; i < NWORK / 4; i += 256) {
      float4 v = c4[i];
      s += (v.x + v.y) + (v.z + v.w);
    }
  }
  float hd_sum = block_reduce_256(s, smr, tid);

  {
    int img = tid >> 4, part = tid & 15;  // 16 threads per image
    float sp = 0.f, st = 0.f, spt = 0.f;
    for (int j = part; j < 64; j += 16) {  // 64 partials/image, 4 iters
      int idx = img * 64 + j;
      sp += spA[idx];
      st += stA[idx];
      spt += sptA[idx];
    }
#pragma unroll
    for (int off = 8; off > 0; off >>= 1) {
      sp += __shfl_down(sp, off, 16);
      st += __shfl_down(st, off, 16);
      spt += __shfl_down(spt, off, 16);
    }
    if (part == 0) {
      smImg[img][0] = sp;
      smImg[img][1] = st;
      smImg[img][2] = spt;
    }
  }
  __syncthreads();
  if (tid < 16) {
    double sp = smImg[tid][0], st = smImg[tid][1], spt = smImg[tid][2];
    double dice = (2.0 * spt + 1e-6) / (sp + st + 1e-6 + 1e-7);
    double tv = (spt + 1e-6) /
                (spt + 0.7 * (sp - spt) + 0.3 * (st - spt) + 1e-6 + 1e-7);
    smd[tid][0] = 1.0 - dice;
    smd[tid][1] = pow(1.0 - tv, 0.75);
  }
  __syncthreads();
  if (tid == 0) {
    double dice_l = 0.0, ft_l = 0.0;
    for (int i = 0; i < 16; ++i) {
      dice_l += smd[i][0];
      ft_l += smd[i][1];
    }
    dice_l /= 16.0;
    ft_l /= 16.0;
    const double Nd = (double)Nc;
    double bce = (double)bce_sum / Nd;
    double hd = ((double)hd_sum / Nd) / (5.5 + 1e-8);
    out[0] = (float)(bce + dice_l + ft_l + 0.1 * hd);
  }
}

}  // namespace

extern "C" void kernel_launch(void* const* d_in, const int* in_sizes, int n_in,
                              void* d_out, int out_size, void* d_ws,
                              size_t ws_size, hipStream_t stream) {
  const float* logits = (const float*)d_in[0];
  const int* target = (const int*)d_in[1];
  float* out = (float*)d_out;

  // Workspace: only small partial arrays (boundary maps never hit global).
  // All slots below are fully written each launch.
  float* part = (float*)d_ws;
  float* bceA = part;                  // 1024
  float* spA = part + NBCE;            // 1024
  float* stA = part + 2 * NBCE;        // 1024
  float* sptA = part + 3 * NBCE;       // 1024
  float* chain_p = part + 4 * NBCE;    // 6656 = 32*16*13 (16B aligned)

  fused_kernel<<<dim3(NBCE + NSB), dim3(256), 0, stream>>>(
      logits, target, bceA, spA, stA, sptA, chain_p);
  finalize_kernel<<<1, 256, 0, stream>>>(bceA, spA, stA, sptA, chain_p, out);
}